// Round 1
// baseline (730.613 us; speedup 1.0000x reference)
//
#include <hip/hip_runtime.h>
#include <math.h>

#define N_NODES 40000
#define N_EDGES 640000
#define DIM     128
#define N_GRAPHS 64
#define N_CLS   100
#define N_LAYERS 3
#define EPSN    1e-12f

// ---------------- CSR build ----------------

__global__ void k_zero_int(int* __restrict__ a, int n) {
    int i = blockIdx.x * blockDim.x + threadIdx.x;
    if (i < n) a[i] = 0;
}

__global__ void k_count(const int* __restrict__ dst, int* __restrict__ counts) {
    int e = blockIdx.x * blockDim.x + threadIdx.x;
    if (e < N_EDGES) atomicAdd(&counts[dst[e]], 1);
}

#define SCAN_T 1024
#define SCAN_V 40   // SCAN_T * SCAN_V >= N_NODES ; N_NODES/SCAN_V = 1000 exact
__global__ void k_scan(const int* __restrict__ counts, int* __restrict__ offsets) {
    __shared__ int lds[SCAN_T];
    int t = threadIdx.x;
    int base = t * SCAN_V;
    int tsum = 0;
    if (base < N_NODES) {
        for (int k = 0; k < SCAN_V; ++k) tsum += counts[base + k];
    }
    // inclusive Hillis-Steele scan of per-thread sums
    lds[t] = tsum; __syncthreads();
    int x = tsum;
    for (int off = 1; off < SCAN_T; off <<= 1) {
        int y = (t >= off) ? lds[t - off] : 0;
        __syncthreads();
        x += y;
        lds[t] = x;
        __syncthreads();
    }
    int excl = x - tsum;
    if (base < N_NODES) {
        int run = excl;
        for (int k = 0; k < SCAN_V; ++k) {
            offsets[base + k] = run;
            run += counts[base + k];
        }
    }
    if (t == (N_NODES / SCAN_V)) offsets[N_NODES] = excl;  // total = E
}

__global__ void k_scatter(const int* __restrict__ src, const int* __restrict__ dst,
                          const int* __restrict__ offsets, int* __restrict__ cursor,
                          int* __restrict__ pos, int* __restrict__ csr_src) {
    int e = blockIdx.x * blockDim.x + threadIdx.x;
    if (e >= N_EDGES) return;
    int d = dst[e];
    int p = offsets[d] + atomicAdd(&cursor[d], 1);
    pos[e] = p;
    csr_src[p] = src[e];
}

// ---------------- per-layer kernels ----------------

// one wave per node: inv[v] = 1/(||h_v|| + eps)
__global__ void k_norm(const float* __restrict__ h, float* __restrict__ inv) {
    int node = (blockIdx.x * blockDim.x + threadIdx.x) >> 6;
    int lane = threadIdx.x & 63;
    if (node >= N_NODES) return;
    const float* row = h + (size_t)node * DIM;
    float x0 = row[lane], x1 = row[lane + 64];
    float ss = x0 * x0 + x1 * x1;
    #pragma unroll
    for (int o = 32; o; o >>= 1) ss += __shfl_xor(ss, o);
    if (lane == 0) inv[node] = 1.0f / (sqrtf(ss) + EPSN);
}

// 16 lanes per edge: score = beta * inv[src]*inv[dst]*dot(h[src],h[dst]),
// written directly into CSR slot pos[e].
__global__ void k_edge_score(const float* __restrict__ h, const float* __restrict__ inv,
                             const int* __restrict__ src, const int* __restrict__ dst,
                             const int* __restrict__ pos,
                             const float* __restrict__ betas, int layer,
                             float* __restrict__ s_csr) {
    int tid = blockIdx.x * blockDim.x + threadIdx.x;
    int e = tid >> 4;
    int l = tid & 15;
    if (e >= N_EDGES) return;
    int vs = src[e], vd = dst[e];
    const float4* rs = (const float4*)(h + (size_t)vs * DIM);
    const float4* rd = (const float4*)(h + (size_t)vd * DIM);
    float4 a0 = rs[l],      b0 = rd[l];
    float4 a1 = rs[l + 16], b1 = rd[l + 16];
    float dot = a0.x * b0.x + a0.y * b0.y + a0.z * b0.z + a0.w * b0.w
              + a1.x * b1.x + a1.y * b1.y + a1.z * b1.z + a1.w * b1.w;
    #pragma unroll
    for (int o = 8; o; o >>= 1) dot += __shfl_xor(dot, o);
    if (l == 0) {
        float sc = betas[layer] * dot * inv[vs] * inv[vd];
        s_csr[pos[e]] = sc;
    }
}

// one wave per node: segment softmax over incoming edges + weighted sum of h[src]
__global__ void k_aggregate(const float* __restrict__ h,
                            const float* __restrict__ s_csr,
                            const int* __restrict__ csr_src,
                            const int* __restrict__ offsets,
                            float* __restrict__ h_out) {
    int node = (blockIdx.x * blockDim.x + threadIdx.x) >> 6;
    int lane = threadIdx.x & 63;
    if (node >= N_NODES) return;
    int off = offsets[node];
    int deg = offsets[node + 1] - off;
    float acc0 = 0.f, acc1 = 0.f;
    if (deg > 0) {
        // per-lane score registers cover up to 128 edges; loop beyond
        float s0 = (lane < deg)      ? s_csr[off + lane]      : -1e30f;
        float s1 = (lane + 64 < deg) ? s_csr[off + lane + 64] : -1e30f;
        float m = fmaxf(s0, s1);
        for (int j = 128 + lane; j < deg; j += 64) m = fmaxf(m, s_csr[off + j]);
        #pragma unroll
        for (int o = 32; o; o >>= 1) m = fmaxf(m, __shfl_xor(m, o));
        float a0 = (lane < deg)      ? __expf(s0 - m) : 0.f;
        float a1 = (lane + 64 < deg) ? __expf(s1 - m) : 0.f;
        float dsum = a0 + a1;
        for (int j = 128 + lane; j < deg; j += 64) dsum += __expf(s_csr[off + j] - m);
        #pragma unroll
        for (int o = 32; o; o >>= 1) dsum += __shfl_xor(dsum, o);

        for (int j = 0; j < deg; ++j) {
            float a;
            if (j < 64)       a = __shfl(a0, j);
            else if (j < 128) a = __shfl(a1, j - 64);
            else              a = __expf(s_csr[off + j] - m);
            int sj = csr_src[off + j];
            const float* row = h + (size_t)sj * DIM;
            acc0 += a * row[lane];
            acc1 += a * row[lane + 64];
        }
        float invd = 1.0f / dsum;   // dsum > 0 when deg > 0
        acc0 *= invd; acc1 *= invd;
    }
    float* orow = h_out + (size_t)node * DIM;
    orow[lane]      = acc0;
    orow[lane + 64] = acc1;
}

// ---------------- readout ----------------

// one block (128 threads) per graph; graph_ids is sorted -> contiguous range
__global__ void k_pool(const float* __restrict__ h, const int* __restrict__ gid,
                       float* __restrict__ hg) {
    int g = blockIdx.x;
    __shared__ int s_start, s_end;
    if (threadIdx.x == 0) {
        int lo = 0, hi = N_NODES;
        while (lo < hi) { int mid = (lo + hi) >> 1; if (gid[mid] < g) lo = mid + 1; else hi = mid; }
        s_start = lo;
        lo = 0; hi = N_NODES;
        while (lo < hi) { int mid = (lo + hi) >> 1; if (gid[mid] < g + 1) lo = mid + 1; else hi = mid; }
        s_end = lo;
    }
    __syncthreads();
    int start = s_start, end = s_end;
    int c = threadIdx.x;  // 0..127 column
    float sum = 0.f;
    for (int n = start; n < end; ++n) sum += h[(size_t)n * DIM + c];
    float cnt = (float)(end - start);
    hg[g * DIM + c] = sum / fmaxf(cnt, 1.0f);
}

__global__ void k_cls(const float* __restrict__ hg, const float* __restrict__ W,
                      const float* __restrict__ b, float* __restrict__ out) {
    int g = blockIdx.x;
    int c = threadIdx.x;
    if (c >= N_CLS) return;
    float acc = b[c];
    #pragma unroll 8
    for (int d = 0; d < DIM; ++d) acc += hg[g * DIM + d] * W[d * N_CLS + c];
    out[g * N_CLS + c] = acc;
}

// ---------------- launch ----------------

extern "C" void kernel_launch(void* const* d_in, const int* in_sizes, int n_in,
                              void* d_out, int out_size, void* d_ws, size_t ws_size,
                              hipStream_t stream) {
    const float* h_in  = (const float*)d_in[0];
    const int*   src   = (const int*)  d_in[1];
    const int*   dst   = (const int*)  d_in[2];
    const int*   gid   = (const int*)  d_in[3];
    const float* betas = (const float*)d_in[4];
    const float* W     = (const float*)d_in[5];
    const float* bcls  = (const float*)d_in[6];
    float* out = (float*)d_out;

    char* p = (char*)d_ws;
    float* h0      = (float*)p; p += (size_t)N_NODES * DIM * 4;   // 20.48 MB
    float* h1      = (float*)p; p += (size_t)N_NODES * DIM * 4;   // 20.48 MB
    float* inv     = (float*)p; p += (size_t)N_NODES * 4;
    float* s_csr   = (float*)p; p += (size_t)N_EDGES * 4;
    int*   counts  = (int*)p;   p += (size_t)N_NODES * 4;
    int*   cursor  = (int*)p;   p += (size_t)N_NODES * 4;         // contiguous with counts
    int*   offsets = (int*)p;   p += (size_t)(N_NODES + 4) * 4;   // N+1 used, padded
    int*   pos     = (int*)p;   p += (size_t)N_EDGES * 4;
    int*   csr_src = (int*)p;   p += (size_t)N_EDGES * 4;
    float* hg      = (float*)p; p += (size_t)N_GRAPHS * DIM * 4;

    // ---- CSR build (src/dst constant across layers) ----
    k_zero_int<<<(2 * N_NODES + 255) / 256, 256, 0, stream>>>(counts, 2 * N_NODES);
    k_count<<<(N_EDGES + 255) / 256, 256, 0, stream>>>(dst, counts);
    k_scan<<<1, SCAN_T, 0, stream>>>(counts, offsets);
    k_scatter<<<(N_EDGES + 255) / 256, 256, 0, stream>>>(src, dst, offsets, cursor, pos, csr_src);

    // ---- 3 AGNN layers ----
    const float* cur = h_in;
    float* bufs[2] = { h0, h1 };
    for (int l = 0; l < N_LAYERS; ++l) {
        float* nxt = bufs[l & 1];
        k_norm<<<N_NODES / 4, 256, 0, stream>>>(cur, inv);
        k_edge_score<<<N_EDGES / 16, 256, 0, stream>>>(cur, inv, src, dst, pos, betas, l, s_csr);
        k_aggregate<<<N_NODES / 4, 256, 0, stream>>>(cur, s_csr, csr_src, offsets, nxt);
        cur = nxt;
    }

    // ---- readout ----
    k_pool<<<N_GRAPHS, DIM, 0, stream>>>(cur, gid, hg);
    k_cls<<<N_GRAPHS, DIM, 0, stream>>>(hg, W, bcls, out);
}

// Round 2
// 589.393 us; speedup vs baseline: 1.2396x; 1.2396x over previous
//
#include <hip/hip_runtime.h>
#include <math.h>

#define N_NODES 40000
#define N_EDGES 640000
#define DIM     128
#define N_GRAPHS 64
#define N_CLS   100
#define N_LAYERS 3
#define EPSN    1e-12f

// ---------------- CSR build ----------------

__global__ void k_zero_int(int* __restrict__ a, int n) {
    int i = blockIdx.x * blockDim.x + threadIdx.x;
    if (i < n) a[i] = 0;
}

__global__ void k_count(const int* __restrict__ dst, int* __restrict__ counts) {
    int e = blockIdx.x * blockDim.x + threadIdx.x;
    if (e < N_EDGES) atomicAdd(&counts[dst[e]], 1);
}

#define SCAN_T 1024
#define SCAN_V 40   // SCAN_T * SCAN_V >= N_NODES ; N_NODES/SCAN_V = 1000 exact
__global__ void k_scan(const int* __restrict__ counts, int* __restrict__ offsets) {
    __shared__ int lds[SCAN_T];
    int t = threadIdx.x;
    int base = t * SCAN_V;
    int tsum = 0;
    if (base < N_NODES) {
        for (int k = 0; k < SCAN_V; ++k) tsum += counts[base + k];
    }
    lds[t] = tsum; __syncthreads();
    int x = tsum;
    for (int off = 1; off < SCAN_T; off <<= 1) {
        int y = (t >= off) ? lds[t - off] : 0;
        __syncthreads();
        x += y;
        lds[t] = x;
        __syncthreads();
    }
    int excl = x - tsum;
    if (base < N_NODES) {
        int run = excl;
        for (int k = 0; k < SCAN_V; ++k) {
            offsets[base + k] = run;
            run += counts[base + k];
        }
    }
    if (t == (N_NODES / SCAN_V)) offsets[N_NODES] = excl;  // total = E
}

__global__ void k_scatter(const int* __restrict__ src, const int* __restrict__ dst,
                          const int* __restrict__ offsets, int* __restrict__ cursor,
                          int* __restrict__ pos, int* __restrict__ csr_src) {
    int e = blockIdx.x * blockDim.x + threadIdx.x;
    if (e >= N_EDGES) return;
    int d = dst[e];
    int p = offsets[d] + atomicAdd(&cursor[d], 1);
    pos[e] = p;
    csr_src[p] = src[e];
}

// ---------------- per-layer kernels ----------------

// one wave per node: inv[v] = 1/(||h_v|| + eps)  (layer 0 only; later layers fused)
__global__ void k_norm(const float* __restrict__ h, float* __restrict__ inv) {
    int node = (blockIdx.x * blockDim.x + threadIdx.x) >> 6;
    int lane = threadIdx.x & 63;
    if (node >= N_NODES) return;
    const float* row = h + (size_t)node * DIM;
    float x0 = row[lane], x1 = row[lane + 64];
    float ss = x0 * x0 + x1 * x1;
    #pragma unroll
    for (int o = 32; o; o >>= 1) ss += __shfl_xor(ss, o);
    if (lane == 0) inv[node] = 1.0f / (sqrtf(ss) + EPSN);
}

// 16 lanes per edge: score = beta * inv[src]*inv[dst]*dot(h[src],h[dst]),
// written directly into CSR slot pos[e].
__global__ void k_edge_score(const float* __restrict__ h, const float* __restrict__ inv,
                             const int* __restrict__ src, const int* __restrict__ dst,
                             const int* __restrict__ pos,
                             const float* __restrict__ betas, int layer,
                             float* __restrict__ s_csr) {
    int tid = blockIdx.x * blockDim.x + threadIdx.x;
    int e = tid >> 4;
    int l = tid & 15;
    if (e >= N_EDGES) return;
    int vs = src[e], vd = dst[e];
    const float4* rs = (const float4*)(h + (size_t)vs * DIM);
    const float4* rd = (const float4*)(h + (size_t)vd * DIM);
    float4 a0 = rs[l],      b0 = rd[l];
    float4 a1 = rs[l + 16], b1 = rd[l + 16];
    float dot = a0.x * b0.x + a0.y * b0.y + a0.z * b0.z + a0.w * b0.w
              + a1.x * b1.x + a1.y * b1.y + a1.z * b1.z + a1.w * b1.w;
    #pragma unroll
    for (int o = 8; o; o >>= 1) dot += __shfl_xor(dot, o);
    if (l == 0) {
        float sc = betas[layer] * dot * inv[vs] * inv[vd];
        s_csr[pos[e]] = sc;
    }
}

// one wave per node: segment softmax + weighted sum of h[src]; also emits
// inv-norm of the OUTPUT row (fused norm for the next layer).
__global__ void k_aggregate(const float* __restrict__ h,
                            const float* __restrict__ s_csr,
                            const int* __restrict__ csr_src,
                            const int* __restrict__ offsets,
                            float* __restrict__ h_out,
                            float* __restrict__ inv_out) {
    int node = (blockIdx.x * blockDim.x + threadIdx.x) >> 6;
    int lane = threadIdx.x & 63;
    if (node >= N_NODES) return;
    int off = offsets[node];
    int deg = offsets[node + 1] - off;
    float acc0 = 0.f, acc1 = 0.f;
    if (deg > 0) {
        float s0 = (lane < deg)      ? s_csr[off + lane]      : -1e30f;
        float s1 = (lane + 64 < deg) ? s_csr[off + lane + 64] : -1e30f;
        float m = fmaxf(s0, s1);
        for (int j = 128 + lane; j < deg; j += 64) m = fmaxf(m, s_csr[off + j]);
        #pragma unroll
        for (int o = 32; o; o >>= 1) m = fmaxf(m, __shfl_xor(m, o));
        float a0 = (lane < deg)      ? __expf(s0 - m) : 0.f;
        float a1 = (lane + 64 < deg) ? __expf(s1 - m) : 0.f;
        float dsum = a0 + a1;
        for (int j = 128 + lane; j < deg; j += 64) dsum += __expf(s_csr[off + j] - m);
        #pragma unroll
        for (int o = 32; o; o >>= 1) dsum += __shfl_xor(dsum, o);

        for (int j = 0; j < deg; ++j) {
            float a;
            if (j < 64)       a = __shfl(a0, j);
            else if (j < 128) a = __shfl(a1, j - 64);
            else              a = __expf(s_csr[off + j] - m);
            int sj = csr_src[off + j];
            const float* row = h + (size_t)sj * DIM;
            acc0 += a * row[lane];
            acc1 += a * row[lane + 64];
        }
        float invd = 1.0f / dsum;
        acc0 *= invd; acc1 *= invd;
    }
    float* orow = h_out + (size_t)node * DIM;
    orow[lane]      = acc0;
    orow[lane + 64] = acc1;
    // fused inv-norm of the output row
    float ss = acc0 * acc0 + acc1 * acc1;
    #pragma unroll
    for (int o = 32; o; o >>= 1) ss += __shfl_xor(ss, o);
    if (lane == 0) inv_out[node] = 1.0f / (sqrtf(ss) + EPSN);
}

// ---------------- readout ----------------

#define POOL_BLOCKS 640
// grid-partitioned pooling: each block owns a contiguous node range, flushes
// per-graph partial sums via atomicAdd only at graph boundaries.
__global__ void k_pool_partial(const float* __restrict__ h, const int* __restrict__ gid,
                               float* __restrict__ hgsum, int* __restrict__ gcount) {
    int nPer = (N_NODES + gridDim.x - 1) / gridDim.x;
    int n0 = blockIdx.x * nPer;
    int n1 = n0 + nPer; if (n1 > N_NODES) n1 = N_NODES;
    if (n0 >= n1) return;
    int c = threadIdx.x;  // 0..127 column
    int curg = gid[n0];
    int segstart = n0;
    float acc = 0.f;
    for (int n = n0; n < n1; ++n) {
        int g = gid[n];
        if (g != curg) {
            atomicAdd(&hgsum[curg * DIM + c], acc);
            if (c == 0) atomicAdd(&gcount[curg], n - segstart);
            acc = 0.f; curg = g; segstart = n;
        }
        acc += h[(size_t)n * DIM + c];
    }
    atomicAdd(&hgsum[curg * DIM + c], acc);
    if (c == 0) atomicAdd(&gcount[curg], n1 - segstart);
}

__global__ void k_cls(const float* __restrict__ hgsum, const int* __restrict__ gcount,
                      const float* __restrict__ W, const float* __restrict__ b,
                      float* __restrict__ out) {
    int g = blockIdx.x;
    int c = threadIdx.x;
    if (c >= N_CLS) return;
    float invc = 1.0f / fmaxf((float)gcount[g], 1.0f);
    float acc = 0.f;
    #pragma unroll 8
    for (int d = 0; d < DIM; ++d) acc += hgsum[g * DIM + d] * W[d * N_CLS + c];
    out[g * N_CLS + c] = b[c] + acc * invc;
}

// ---------------- launch ----------------

extern "C" void kernel_launch(void* const* d_in, const int* in_sizes, int n_in,
                              void* d_out, int out_size, void* d_ws, size_t ws_size,
                              hipStream_t stream) {
    const float* h_in  = (const float*)d_in[0];
    const int*   src   = (const int*)  d_in[1];
    const int*   dst   = (const int*)  d_in[2];
    const int*   gid   = (const int*)  d_in[3];
    const float* betas = (const float*)d_in[4];
    const float* W     = (const float*)d_in[5];
    const float* bcls  = (const float*)d_in[6];
    float* out = (float*)d_out;

    char* p = (char*)d_ws;
    float* h0      = (float*)p; p += (size_t)N_NODES * DIM * 4;   // 20.48 MB
    float* h1      = (float*)p; p += (size_t)N_NODES * DIM * 4;   // 20.48 MB
    float* inv     = (float*)p; p += (size_t)N_NODES * 4;
    float* s_csr   = (float*)p; p += (size_t)N_EDGES * 4;
    int*   counts  = (int*)p;   p += (size_t)N_NODES * 4;
    int*   cursor  = (int*)p;   p += (size_t)N_NODES * 4;         // contiguous with counts
    int*   offsets = (int*)p;   p += (size_t)(N_NODES + 4) * 4;   // N+1 used, padded
    int*   pos     = (int*)p;   p += (size_t)N_EDGES * 4;
    int*   csr_src = (int*)p;   p += (size_t)N_EDGES * 4;
    float* hgsum   = (float*)p; p += (size_t)N_GRAPHS * DIM * 4;  // contiguous with gcount
    int*   gcount  = (int*)p;   p += (size_t)N_GRAPHS * 4;

    // ---- CSR build (src/dst constant across layers) ----
    k_zero_int<<<(2 * N_NODES + 255) / 256, 256, 0, stream>>>(counts, 2 * N_NODES);
    k_count<<<(N_EDGES + 255) / 256, 256, 0, stream>>>(dst, counts);
    k_scan<<<1, SCAN_T, 0, stream>>>(counts, offsets);
    k_scatter<<<(N_EDGES + 255) / 256, 256, 0, stream>>>(src, dst, offsets, cursor, pos, csr_src);
    // zero pooling accumulators (8192 floats + 64 ints, contiguous)
    k_zero_int<<<(N_GRAPHS * DIM + N_GRAPHS + 255) / 256, 256, 0, stream>>>((int*)hgsum, N_GRAPHS * DIM + N_GRAPHS);

    // ---- 3 AGNN layers ----
    const float* cur = h_in;
    float* bufs[2] = { h0, h1 };
    k_norm<<<N_NODES / 4, 256, 0, stream>>>(cur, inv);   // layer-0 input norm
    for (int l = 0; l < N_LAYERS; ++l) {
        float* nxt = bufs[l & 1];
        k_edge_score<<<N_EDGES / 16, 256, 0, stream>>>(cur, inv, src, dst, pos, betas, l, s_csr);
        k_aggregate<<<N_NODES / 4, 256, 0, stream>>>(cur, s_csr, csr_src, offsets, nxt, inv);
        cur = nxt;
    }

    // ---- readout ----
    k_pool_partial<<<POOL_BLOCKS, DIM, 0, stream>>>(cur, gid, hgsum, gcount);
    k_cls<<<N_GRAPHS, DIM, 0, stream>>>(hgsum, gcount, W, bcls, out);
}

// Round 4
// 285.435 us; speedup vs baseline: 2.5596x; 2.0649x over previous
//
#include <hip/hip_runtime.h>
#include <math.h>

#define N_NODES 40000
#define N_EDGES 640000
#define DIM     128
#define N_GRAPHS 64
#define N_CLS   100
#define N_LAYERS 3
#define EPSN    1e-12f

// ---------------- CSR build ----------------

__global__ void k_zero_int(int* __restrict__ a, int n) {
    int i = blockIdx.x * blockDim.x + threadIdx.x;
    if (i < n) a[i] = 0;
}

__global__ void k_count(const int* __restrict__ dst, int* __restrict__ counts) {
    int e = blockIdx.x * blockDim.x + threadIdx.x;
    if (e < N_EDGES) atomicAdd(&counts[dst[e]], 1);
}

#define SCAN_T 1024
#define SCAN_V 40   // SCAN_T * SCAN_V >= N_NODES ; N_NODES/SCAN_V = 1000 exact
__global__ void k_scan(const int* __restrict__ counts, int* __restrict__ offsets) {
    __shared__ int lds[SCAN_T];
    int t = threadIdx.x;
    int base = t * SCAN_V;
    int tsum = 0;
    if (base < N_NODES) {
        for (int k = 0; k < SCAN_V; ++k) tsum += counts[base + k];
    }
    lds[t] = tsum; __syncthreads();
    int x = tsum;
    for (int off = 1; off < SCAN_T; off <<= 1) {
        int y = (t >= off) ? lds[t - off] : 0;
        __syncthreads();
        x += y;
        lds[t] = x;
        __syncthreads();
    }
    int excl = x - tsum;
    if (base < N_NODES) {
        int run = excl;
        for (int k = 0; k < SCAN_V; ++k) {
            offsets[base + k] = run;
            run += counts[base + k];
        }
    }
    if (t == (N_NODES / SCAN_V)) offsets[N_NODES] = excl;  // total = E
}

__global__ void k_scatter(const int* __restrict__ src, const int* __restrict__ dst,
                          const int* __restrict__ offsets, int* __restrict__ cursor,
                          int* __restrict__ csr_src) {
    int e = blockIdx.x * blockDim.x + threadIdx.x;
    if (e >= N_EDGES) return;
    int d = dst[e];
    int p = offsets[d] + atomicAdd(&cursor[d], 1);
    csr_src[p] = src[e];
}

// ---------------- per-layer kernels ----------------

// one wave per node: inv[v] = 1/(||h_v|| + eps)  (layer-0 input only)
__global__ void k_norm(const float* __restrict__ h, float* __restrict__ inv) {
    int node = (blockIdx.x * blockDim.x + threadIdx.x) >> 6;
    int lane = threadIdx.x & 63;
    if (node >= N_NODES) return;
    const float* row = h + (size_t)node * DIM;
    float x0 = row[lane], x1 = row[lane + 64];
    float ss = x0 * x0 + x1 * x1;
    #pragma unroll
    for (int o = 32; o; o >>= 1) ss += __shfl_xor(ss, o);
    if (lane == 0) inv[node] = 1.0f / (sqrtf(ss) + EPSN);
}

// Fused edge-score + segment-softmax + aggregate, one wave per node.
// Lane l owns feature elements [2l, 2l+1] (float2). Per in-edge: one 8B
// gather/lane, dot via 6-step shfl_xor butterfly, branchless online softmax.
// inv is DOUBLE-BUFFERED across layers: inv_in is read for scores, inv_out
// (a different buffer) receives the output row's inv-norm.
#define ONLINE(sc, r) do {                                         \
    float mn = fmaxf(m, sc);                                       \
    float c = __expf(m - mn);                                      \
    float w = __expf(sc - mn);                                     \
    dsum = dsum * c + w;                                           \
    accx = accx * c + w * (r).x;                                   \
    accy = accy * c + w * (r).y;                                   \
    m = mn;                                                        \
} while (0)

__global__ void k_fused(const float* __restrict__ h,
                        const float* __restrict__ inv_in,
                        const int* __restrict__ csr_src,
                        const int* __restrict__ offsets,
                        const float* __restrict__ betas, int layer,
                        float* __restrict__ h_out,
                        float* __restrict__ inv_out) {
    int node = (blockIdx.x * blockDim.x + threadIdx.x) >> 6;
    int lane = threadIdx.x & 63;
    if (node >= N_NODES) return;
    int off = offsets[node];
    int deg = offsets[node + 1] - off;

    const float2* h2 = (const float2*)h;
    float2 hd = h2[(size_t)node * 64 + lane];
    float bi = betas[layer] * inv_in[node];

    float accx = 0.f, accy = 0.f, dsum = 0.f, m = -1e30f;

    int j = 0;
    for (; j + 4 <= deg; j += 4) {
        int s0 = csr_src[off + j],     s1 = csr_src[off + j + 1];
        int s2 = csr_src[off + j + 2], s3 = csr_src[off + j + 3];
        float2 r0 = h2[(size_t)s0 * 64 + lane];
        float2 r1 = h2[(size_t)s1 * 64 + lane];
        float2 r2 = h2[(size_t)s2 * 64 + lane];
        float2 r3 = h2[(size_t)s3 * 64 + lane];
        float p0 = r0.x * hd.x + r0.y * hd.y;
        float p1 = r1.x * hd.x + r1.y * hd.y;
        float p2 = r2.x * hd.x + r2.y * hd.y;
        float p3 = r3.x * hd.x + r3.y * hd.y;
        #pragma unroll
        for (int o = 32; o; o >>= 1) {
            p0 += __shfl_xor(p0, o);
            p1 += __shfl_xor(p1, o);
            p2 += __shfl_xor(p2, o);
            p3 += __shfl_xor(p3, o);
        }
        float sc0 = bi * inv_in[s0] * p0;
        float sc1 = bi * inv_in[s1] * p1;
        float sc2 = bi * inv_in[s2] * p2;
        float sc3 = bi * inv_in[s3] * p3;
        ONLINE(sc0, r0);
        ONLINE(sc1, r1);
        ONLINE(sc2, r2);
        ONLINE(sc3, r3);
    }
    for (; j < deg; ++j) {
        int sj = csr_src[off + j];
        float2 r = h2[(size_t)sj * 64 + lane];
        float p = r.x * hd.x + r.y * hd.y;
        #pragma unroll
        for (int o = 32; o; o >>= 1) p += __shfl_xor(p, o);
        float sc = bi * inv_in[sj] * p;
        ONLINE(sc, r);
    }

    float invd = (deg > 0) ? 1.0f / dsum : 0.f;
    accx *= invd; accy *= invd;
    float2* orow = (float2*)h_out + (size_t)node * 64;
    orow[lane] = make_float2(accx, accy);

    // fused inv-norm of the output row (for next layer's scores)
    float ss = accx * accx + accy * accy;
    #pragma unroll
    for (int o = 32; o; o >>= 1) ss += __shfl_xor(ss, o);
    if (lane == 0) inv_out[node] = 1.0f / (sqrtf(ss) + EPSN);
}

// ---------------- readout ----------------

#define POOL_BLOCKS 640
__global__ void k_pool_partial(const float* __restrict__ h, const int* __restrict__ gid,
                               float* __restrict__ hgsum, int* __restrict__ gcount) {
    int nPer = (N_NODES + gridDim.x - 1) / gridDim.x;
    int n0 = blockIdx.x * nPer;
    int n1 = n0 + nPer; if (n1 > N_NODES) n1 = N_NODES;
    if (n0 >= n1) return;
    int c = threadIdx.x;  // 0..127 column
    int curg = gid[n0];
    int segstart = n0;
    float acc = 0.f;
    for (int n = n0; n < n1; ++n) {
        int g = gid[n];
        if (g != curg) {
            atomicAdd(&hgsum[curg * DIM + c], acc);
            if (c == 0) atomicAdd(&gcount[curg], n - segstart);
            acc = 0.f; curg = g; segstart = n;
        }
        acc += h[(size_t)n * DIM + c];
    }
    atomicAdd(&hgsum[curg * DIM + c], acc);
    if (c == 0) atomicAdd(&gcount[curg], n1 - segstart);
}

__global__ void k_cls(const float* __restrict__ hgsum, const int* __restrict__ gcount,
                      const float* __restrict__ W, const float* __restrict__ b,
                      float* __restrict__ out) {
    int g = blockIdx.x;
    int c = threadIdx.x;
    if (c >= N_CLS) return;
    float invc = 1.0f / fmaxf((float)gcount[g], 1.0f);
    float acc = 0.f;
    #pragma unroll 8
    for (int d = 0; d < DIM; ++d) acc += hgsum[g * DIM + d] * W[d * N_CLS + c];
    out[g * N_CLS + c] = b[c] + acc * invc;
}

// ---------------- launch ----------------

extern "C" void kernel_launch(void* const* d_in, const int* in_sizes, int n_in,
                              void* d_out, int out_size, void* d_ws, size_t ws_size,
                              hipStream_t stream) {
    const float* h_in  = (const float*)d_in[0];
    const int*   src   = (const int*)  d_in[1];
    const int*   dst   = (const int*)  d_in[2];
    const int*   gid   = (const int*)  d_in[3];
    const float* betas = (const float*)d_in[4];
    const float* W     = (const float*)d_in[5];
    const float* bcls  = (const float*)d_in[6];
    float* out = (float*)d_out;

    char* p = (char*)d_ws;
    float* h0      = (float*)p; p += (size_t)N_NODES * DIM * 4;   // 20.48 MB
    float* h1      = (float*)p; p += (size_t)N_NODES * DIM * 4;   // 20.48 MB
    float* inv0    = (float*)p; p += (size_t)N_NODES * 4;
    float* inv1    = (float*)p; p += (size_t)N_NODES * 4;
    int*   counts  = (int*)p;   p += (size_t)N_NODES * 4;
    int*   cursor  = (int*)p;   p += (size_t)N_NODES * 4;         // contiguous with counts
    int*   offsets = (int*)p;   p += (size_t)(N_NODES + 4) * 4;   // N+1 used, padded
    int*   csr_src = (int*)p;   p += (size_t)N_EDGES * 4;
    float* hgsum   = (float*)p; p += (size_t)N_GRAPHS * DIM * 4;  // contiguous with gcount
    int*   gcount  = (int*)p;   p += (size_t)N_GRAPHS * 4;

    // ---- CSR build (src/dst constant across layers) ----
    k_zero_int<<<(2 * N_NODES + 255) / 256, 256, 0, stream>>>(counts, 2 * N_NODES);
    k_count<<<(N_EDGES + 255) / 256, 256, 0, stream>>>(dst, counts);
    k_scan<<<1, SCAN_T, 0, stream>>>(counts, offsets);
    k_scatter<<<(N_EDGES + 255) / 256, 256, 0, stream>>>(src, dst, offsets, cursor, csr_src);
    // zero pooling accumulators (8192 floats + 64 ints, contiguous)
    k_zero_int<<<(N_GRAPHS * DIM + N_GRAPHS + 255) / 256, 256, 0, stream>>>((int*)hgsum, N_GRAPHS * DIM + N_GRAPHS);

    // ---- 3 AGNN layers (fused score+softmax+aggregate; h AND inv double-buffered) ----
    const float* cur = h_in;
    float* hbufs[2]   = { h0, h1 };
    float* invbufs[2] = { inv0, inv1 };
    k_norm<<<N_NODES / 4, 256, 0, stream>>>(cur, invbufs[0]);   // layer-0 input norm
    for (int l = 0; l < N_LAYERS; ++l) {
        float* nxt = hbufs[l & 1];
        k_fused<<<N_NODES / 4, 256, 0, stream>>>(cur, invbufs[l & 1],
                                                 csr_src, offsets, betas, l,
                                                 nxt, invbufs[(l + 1) & 1]);
        cur = nxt;
    }

    // ---- readout ----
    k_pool_partial<<<POOL_BLOCKS, DIM, 0, stream>>>(cur, gid, hgsum, gcount);
    k_cls<<<N_GRAPHS, DIM, 0, stream>>>(hgsum, gcount, W, bcls, out);
}

// Round 5
// 256.249 us; speedup vs baseline: 2.8512x; 1.1139x over previous
//
#include <hip/hip_runtime.h>
#include <math.h>

#define N_NODES 40000
#define N_EDGES 640000
#define DIM     128
#define N_GRAPHS 64
#define N_CLS   100
#define N_LAYERS 3
#define EPSN    1e-12f

// ---------------- CSR build ----------------

__global__ void k_zero_int(int* __restrict__ a, int n) {
    int i = blockIdx.x * blockDim.x + threadIdx.x;
    if (i < n) a[i] = 0;
}

__global__ void k_count(const int* __restrict__ dst, int* __restrict__ counts) {
    int e = blockIdx.x * blockDim.x + threadIdx.x;
    if (e < N_EDGES) atomicAdd(&counts[dst[e]], 1);
}

#define SCAN_T 1024
#define SCAN_V 40   // SCAN_T * SCAN_V >= N_NODES ; N_NODES/SCAN_V = 1000 exact
__global__ void k_scan(const int* __restrict__ counts, int* __restrict__ offsets) {
    __shared__ int lds[SCAN_T];
    int t = threadIdx.x;
    int base = t * SCAN_V;
    int tsum = 0;
    if (base < N_NODES) {
        for (int k = 0; k < SCAN_V; ++k) tsum += counts[base + k];
    }
    lds[t] = tsum; __syncthreads();
    int x = tsum;
    for (int off = 1; off < SCAN_T; off <<= 1) {
        int y = (t >= off) ? lds[t - off] : 0;
        __syncthreads();
        x += y;
        lds[t] = x;
        __syncthreads();
    }
    int excl = x - tsum;
    if (base < N_NODES) {
        int run = excl;
        for (int k = 0; k < SCAN_V; ++k) {
            offsets[base + k] = run;
            run += counts[base + k];
        }
    }
    if (t == (N_NODES / SCAN_V)) offsets[N_NODES] = excl;  // total = E
}

__global__ void k_scatter(const int* __restrict__ src, const int* __restrict__ dst,
                          const int* __restrict__ offsets, int* __restrict__ cursor,
                          int* __restrict__ csr_src) {
    int e = blockIdx.x * blockDim.x + threadIdx.x;
    if (e >= N_EDGES) return;
    int d = dst[e];
    int p = offsets[d] + atomicAdd(&cursor[d], 1);
    csr_src[p] = src[e];
}

// ---------------- per-layer kernels ----------------

// one wave per node: inv[v] = 1/(||h_v|| + eps)  (layer-0 input only)
__global__ void k_norm(const float* __restrict__ h, float* __restrict__ inv) {
    int node = (blockIdx.x * blockDim.x + threadIdx.x) >> 6;
    int lane = threadIdx.x & 63;
    if (node >= N_NODES) return;
    const float* row = h + (size_t)node * DIM;
    float x0 = row[lane], x1 = row[lane + 64];
    float ss = x0 * x0 + x1 * x1;
    #pragma unroll
    for (int o = 32; o; o >>= 1) ss += __shfl_xor(ss, o);
    if (lane == 0) inv[node] = 1.0f / (sqrtf(ss) + EPSN);
}

// Fused edge-score + segment-softmax + aggregate.
// One wave per node; wave = 4 groups of 16 lanes; each group processes one
// edge at a time. Lane t owns features [4t..4t+3] and [64+4t..64+4t+3].
// Scores = beta * cosine in [-1,1], so exp(sc) is bounded: no max-subtraction
// needed (softmax is shift-invariant; matches reference math exactly).
__device__ __forceinline__ float dot8(float4 a0, float4 a1, float4 b0, float4 b1) {
    return a0.x * b0.x + a0.y * b0.y + a0.z * b0.z + a0.w * b0.w
         + a1.x * b1.x + a1.y * b1.y + a1.z * b1.z + a1.w * b1.w;
}

__global__ void k_fused(const float* __restrict__ h,
                        const float* __restrict__ inv_in,
                        const int* __restrict__ csr_src,
                        const int* __restrict__ offsets,
                        const float* __restrict__ betas, int layer,
                        float* __restrict__ h_out,
                        float* __restrict__ inv_out) {
    int node = (blockIdx.x * blockDim.x + threadIdx.x) >> 6;
    int lane = threadIdx.x & 63;
    if (node >= N_NODES) return;
    int grp = lane >> 4;   // 0..3: which edge of the 4-in-flight
    int t   = lane & 15;   // feature sublane

    int off = offsets[node];
    int deg = offsets[node + 1] - off;

    const float4* h4 = (const float4*)h;
    size_t nrow = (size_t)node * 32;
    float4 hda = h4[nrow + t];
    float4 hdb = h4[nrow + 16 + t];
    float bi = betas[layer] * inv_in[node];

    float dsum = 0.f;
    float4 accA = make_float4(0.f, 0.f, 0.f, 0.f);
    float4 accB = make_float4(0.f, 0.f, 0.f, 0.f);

    int jb = 0;
    // full iterations: 8 edges per pass (2 per group), no bounds checks
    for (; jb + 8 <= deg; jb += 8) {
        int s0 = csr_src[off + jb + grp];
        int s1 = csr_src[off + jb + 4 + grp];
        size_t r0 = (size_t)s0 * 32, r1 = (size_t)s1 * 32;
        float4 r0a = h4[r0 + t], r0b = h4[r0 + 16 + t];
        float4 r1a = h4[r1 + t], r1b = h4[r1 + 16 + t];
        float iv0 = inv_in[s0], iv1 = inv_in[s1];
        float p0 = dot8(r0a, r0b, hda, hdb);
        float p1 = dot8(r1a, r1b, hda, hdb);
        #pragma unroll
        for (int o = 8; o; o >>= 1) {
            p0 += __shfl_xor(p0, o);
            p1 += __shfl_xor(p1, o);
        }
        float w0 = __expf(bi * iv0 * p0);
        float w1 = __expf(bi * iv1 * p1);
        dsum += w0 + w1;
        accA.x += w0 * r0a.x + w1 * r1a.x;
        accA.y += w0 * r0a.y + w1 * r1a.y;
        accA.z += w0 * r0a.z + w1 * r1a.z;
        accA.w += w0 * r0a.w + w1 * r1a.w;
        accB.x += w0 * r0b.x + w1 * r1b.x;
        accB.y += w0 * r0b.y + w1 * r1b.y;
        accB.z += w0 * r0b.z + w1 * r1b.z;
        accB.w += w0 * r0b.w + w1 * r1b.w;
    }
    // clamped tail: up to 2 passes of 4 edges, invalid groups contribute w=0
    for (; jb < deg; jb += 4) {
        int j = jb + grp;
        bool valid = j < deg;
        int idx = valid ? j : (deg - 1);
        int s = csr_src[off + idx];
        size_t r = (size_t)s * 32;
        float4 ra = h4[r + t], rb = h4[r + 16 + t];
        float iv = inv_in[s];
        float p = dot8(ra, rb, hda, hdb);
        #pragma unroll
        for (int o = 8; o; o >>= 1) p += __shfl_xor(p, o);
        float w = valid ? __expf(bi * iv * p) : 0.f;
        dsum += w;
        accA.x += w * ra.x; accA.y += w * ra.y;
        accA.z += w * ra.z; accA.w += w * ra.w;
        accB.x += w * rb.x; accB.y += w * rb.y;
        accB.z += w * rb.z; accB.w += w * rb.w;
    }

    // merge the 4 group partials (plain sums — no max bookkeeping)
    #pragma unroll
    for (int o = 16; o < 64; o <<= 1) {
        dsum   += __shfl_xor(dsum, o);
        accA.x += __shfl_xor(accA.x, o);
        accA.y += __shfl_xor(accA.y, o);
        accA.z += __shfl_xor(accA.z, o);
        accA.w += __shfl_xor(accA.w, o);
        accB.x += __shfl_xor(accB.x, o);
        accB.y += __shfl_xor(accB.y, o);
        accB.z += __shfl_xor(accB.z, o);
        accB.w += __shfl_xor(accB.w, o);
    }

    float invd = (deg > 0) ? 1.0f / dsum : 0.f;
    accA.x *= invd; accA.y *= invd; accA.z *= invd; accA.w *= invd;
    accB.x *= invd; accB.y *= invd; accB.z *= invd; accB.w *= invd;

    if (grp == 0) {
        float4* o4 = (float4*)h_out + nrow;
        o4[t]      = accA;
        o4[16 + t] = accB;
    }

    // fused inv-norm of the output row (for next layer's scores)
    float ss = accA.x * accA.x + accA.y * accA.y + accA.z * accA.z + accA.w * accA.w
             + accB.x * accB.x + accB.y * accB.y + accB.z * accB.z + accB.w * accB.w;
    #pragma unroll
    for (int o = 8; o; o >>= 1) ss += __shfl_xor(ss, o);
    if (lane == 0) inv_out[node] = 1.0f / (sqrtf(ss) + EPSN);
}

// ---------------- readout ----------------

#define POOL_BLOCKS 640
__global__ void k_pool_partial(const float* __restrict__ h, const int* __restrict__ gid,
                               float* __restrict__ hgsum, int* __restrict__ gcount) {
    int nPer = (N_NODES + gridDim.x - 1) / gridDim.x;
    int n0 = blockIdx.x * nPer;
    int n1 = n0 + nPer; if (n1 > N_NODES) n1 = N_NODES;
    if (n0 >= n1) return;
    int c = threadIdx.x;  // 0..127 column
    int curg = gid[n0];
    int segstart = n0;
    float acc = 0.f;
    for (int n = n0; n < n1; ++n) {
        int g = gid[n];
        if (g != curg) {
            atomicAdd(&hgsum[curg * DIM + c], acc);
            if (c == 0) atomicAdd(&gcount[curg], n - segstart);
            acc = 0.f; curg = g; segstart = n;
        }
        acc += h[(size_t)n * DIM + c];
    }
    atomicAdd(&hgsum[curg * DIM + c], acc);
    if (c == 0) atomicAdd(&gcount[curg], n1 - segstart);
}

__global__ void k_cls(const float* __restrict__ hgsum, const int* __restrict__ gcount,
                      const float* __restrict__ W, const float* __restrict__ b,
                      float* __restrict__ out) {
    int g = blockIdx.x;
    int c = threadIdx.x;
    if (c >= N_CLS) return;
    float invc = 1.0f / fmaxf((float)gcount[g], 1.0f);
    float acc = 0.f;
    #pragma unroll 8
    for (int d = 0; d < DIM; ++d) acc += hgsum[g * DIM + d] * W[d * N_CLS + c];
    out[g * N_CLS + c] = b[c] + acc * invc;
}

// ---------------- launch ----------------

extern "C" void kernel_launch(void* const* d_in, const int* in_sizes, int n_in,
                              void* d_out, int out_size, void* d_ws, size_t ws_size,
                              hipStream_t stream) {
    const float* h_in  = (const float*)d_in[0];
    const int*   src   = (const int*)  d_in[1];
    const int*   dst   = (const int*)  d_in[2];
    const int*   gid   = (const int*)  d_in[3];
    const float* betas = (const float*)d_in[4];
    const float* W     = (const float*)d_in[5];
    const float* bcls  = (const float*)d_in[6];
    float* out = (float*)d_out;

    char* p = (char*)d_ws;
    float* h0      = (float*)p; p += (size_t)N_NODES * DIM * 4;   // 20.48 MB
    float* h1      = (float*)p; p += (size_t)N_NODES * DIM * 4;   // 20.48 MB
    float* inv0    = (float*)p; p += (size_t)N_NODES * 4;
    float* inv1    = (float*)p; p += (size_t)N_NODES * 4;
    // --- contiguous zero-init region ---
    int*   counts  = (int*)p;   p += (size_t)N_NODES * 4;
    int*   cursor  = (int*)p;   p += (size_t)N_NODES * 4;
    float* hgsum   = (float*)p; p += (size_t)N_GRAPHS * DIM * 4;
    int*   gcount  = (int*)p;   p += (size_t)N_GRAPHS * 4;
    // -----------------------------------
    int*   offsets = (int*)p;   p += (size_t)(N_NODES + 4) * 4;   // N+1 used, padded
    int*   csr_src = (int*)p;   p += (size_t)N_EDGES * 4;

    const int ZERO_N = 2 * N_NODES + N_GRAPHS * DIM + N_GRAPHS;

    // ---- CSR build (src/dst constant across layers) ----
    k_zero_int<<<(ZERO_N + 255) / 256, 256, 0, stream>>>(counts, ZERO_N);
    k_count<<<(N_EDGES + 255) / 256, 256, 0, stream>>>(dst, counts);
    k_scan<<<1, SCAN_T, 0, stream>>>(counts, offsets);
    k_scatter<<<(N_EDGES + 255) / 256, 256, 0, stream>>>(src, dst, offsets, cursor, csr_src);

    // ---- 3 AGNN layers (fused score+softmax+aggregate; h AND inv double-buffered) ----
    const float* cur = h_in;
    float* hbufs[2]   = { h0, h1 };
    float* invbufs[2] = { inv0, inv1 };
    k_norm<<<N_NODES / 4, 256, 0, stream>>>(cur, invbufs[0]);   // layer-0 input norm
    for (int l = 0; l < N_LAYERS; ++l) {
        float* nxt = hbufs[l & 1];
        k_fused<<<N_NODES / 4, 256, 0, stream>>>(cur, invbufs[l & 1],
                                                 csr_src, offsets, betas, l,
                                                 nxt, invbufs[(l + 1) & 1]);
        cur = nxt;
    }

    // ---- readout ----
    k_pool_partial<<<POOL_BLOCKS, DIM, 0, stream>>>(cur, gid, hgsum, gcount);
    k_cls<<<N_GRAPHS, DIM, 0, stream>>>(hgsum, gcount, W, bcls, out);
}